// Round 9
// baseline (259.562 us; speedup 1.0000x reference)
//
#include <hip/hip_runtime.h>

// v9: PERSISTENT GRID-STRIDE. v8's per-wave barrier-free body, but 2048
// long-lived blocks (copy-ubench shape) instead of 7813 short-lived ones.
// Rationale: 8 structurally distinct kernels pinned at 3.1 TB/s = half the
// m13 copy reference; every per-CU lever (MLP/occupancy/shape/sync/policy)
// falsified. Last untested axis: work-distribution quantum. Short blocks
// (~3us life, 35KB traffic) pay drain+refill dead time per generation
// (~30 gens/CU) that copy's persistent grid-stride never pays.
#define PTS 256
#define NBLOCKS 2048

__global__ __launch_bounds__(256) void cov_proj_kernel(
    const float4* __restrict__ rot,     // (N,4) as float4
    const float*  __restrict__ mod,     // (1,)
    const float2* __restrict__ scale,   // (N,2) as float2
    const float*  __restrict__ p_k,     // (N,3)
    const float4* __restrict__ vm,      // (N,16) as 4x float4 per row
    float*        __restrict__ out,     // (N,9)
    int n)
{
    __shared__ __attribute__((aligned(16))) float lds_out[PTS * 9];  // 9 KiB

    const int t = threadIdx.x;
    const int w = t >> 6;               // wave id 0..3
    const int l = t & 63;               // lane id
    const int stride = gridDim.x * PTS; // points per generation
    const float m = mod[0];             // hoisted: one scalar load

    float* wlds = &lds_out[w * 576];    // this wave's private 576-float slice

    for (int base = blockIdx.x * PTS; base < n; base += stride) {
        const int i = base + t;

        if (i < n) {
            float4 q = rot[i];
            float r = q.x, x = q.y, y = q.z, z = q.w;
            float2 sc = scale[i];
            float s0 = m * sc.x;
            float s1 = m * sc.y;

            float R00 = 1.0f - 2.0f * (y * y + z * z);
            float R10 = 2.0f * (x * y + r * z);
            float R20 = 2.0f * (x * z - r * y);
            float R01 = 2.0f * (x * y - r * z);
            float R11 = 1.0f - 2.0f * (x * x + z * z);
            float R21 = 2.0f * (y * z + r * x);

            float u0 = s0 * R00, u1 = s0 * R10, u2 = s0 * R20;
            float v0 = s1 * R01, v1 = s1 * R11, v2 = s1 * R21;

            float p0 = p_k[3 * i + 0];
            float p1 = p_k[3 * i + 1];
            float p2 = p_k[3 * i + 2];

            float4 vm0 = vm[4 * i + 0];
            float4 vm1 = vm[4 * i + 1];
            float4 vm2 = vm[4 * i + 2];
            float4 vm3 = vm[4 * i + 3];

            float* o = &wlds[9 * l];    // banks (9l+j)%32: <=2 lanes/bank -> free
            o[0] = vm0.x * u0 + vm1.x * u1 + vm2.x * u2;
            o[1] = vm0.x * v0 + vm1.x * v1 + vm2.x * v2;
            o[2] = vm0.x * p0 + vm1.x * p1 + vm2.x * p2 + vm3.x;
            o[3] = vm0.y * u0 + vm1.y * u1 + vm2.y * u2;
            o[4] = vm0.y * v0 + vm1.y * v1 + vm2.y * v2;
            o[5] = vm0.y * p0 + vm1.y * p1 + vm2.y * p2 + vm3.y;
            o[6] = vm0.z * u0 + vm1.z * u1 + vm2.z * u2;
            o[7] = vm0.z * v0 + vm1.z * v1 + vm2.z * v2;
            o[8] = vm0.z * p0 + vm1.z * p1 + vm2.z * p2 + vm3.z;
        }

        // In-wave fence (v8, proven correct): lanes are lockstep within a
        // CDNA wave; lgkmcnt(0) lands ds_writes before cross-lane ds_reads,
        // sched_barrier stops hoisting (rule 18).
        asm volatile("s_waitcnt lgkmcnt(0)" ::: "memory");
        __builtin_amdgcn_sched_barrier(0);

        const int g0 = base + w * 64;           // wave's first point
        if (g0 + 64 <= n) {
            // Full wave: 64 pts x 9 = 576 floats = 144 float4, contiguous.
            // Byte base (base+w*64)*36: base*36 = blk*9216 (16-al.), w*2304 (16-al.)
            const float4* lw4 = (const float4*)wlds;
            float4* gw4 = (float4*)(out + (size_t)g0 * 9);
            gw4[l]       = lw4[l];
            gw4[64 + l]  = lw4[64 + l];
            if (l < 16) gw4[128 + l] = lw4[128 + l];
        } else if (g0 < n) {
            // Ragged tail wave (unused: n % 64 == 0; kept for correctness).
            const int cnt = (n - g0) * 9;
            for (int k = l; k < cnt; k += 64) out[(size_t)g0 * 9 + k] = wlds[k];
        }
        // No cross-wave hazard: each wave re-writes only its own LDS slice.
    }
}

extern "C" void kernel_launch(void* const* d_in, const int* in_sizes, int n_in,
                              void* d_out, int out_size, void* d_ws, size_t ws_size,
                              hipStream_t stream) {
    const float4* rot   = (const float4*)d_in[0];
    const float*  mod   = (const float*)d_in[1];
    const float2* scale = (const float2*)d_in[2];
    const float*  p_k   = (const float*)d_in[3];
    const float4* vm    = (const float4*)d_in[4];
    float* out = (float*)d_out;

    int n = in_sizes[0] / 4;  // rot has N*4 elements
    int block = 256;
    int total_blocks = (n + PTS - 1) / PTS;
    int grid = total_blocks < NBLOCKS ? total_blocks : NBLOCKS;
    cov_proj_kernel<<<grid, block, 0, stream>>>(rot, mod, scale, p_k, vm, out, n);
}